// Round 5
// baseline (437.985 us; speedup 1.0000x reference)
//
#include <hip/hip_runtime.h>
#include <float.h>

#define S_  4096
#define B_  8
#define D_  768
#define H_  12
#define HD_ 64
#define W_  128
#define BH_ 96
#define SB_ 32768

typedef unsigned short u16;
typedef __attribute__((ext_vector_type(8))) short bf16x8;
typedef __attribute__((ext_vector_type(4))) float f32x4;

#define MFMA16(a,b,c) __builtin_amdgcn_mfma_f32_16x16x32_bf16(a,b,c,0,0,0)

// f32 -> bf16 round-to-nearest-even
__device__ __forceinline__ u16 f2bf(float x){
  unsigned int u = __float_as_uint(x);
  return (u16)((u + 0x7FFFu + ((u >> 16) & 1u)) >> 16);
}
__device__ __forceinline__ float bf2f(unsigned int lo16){ return __uint_as_float(lo16 << 16); }
__device__ __forceinline__ float bflo(unsigned int u){ return __uint_as_float(u << 16); }
__device__ __forceinline__ float bfhi(unsigned int u){ return __uint_as_float(u & 0xFFFF0000u); }
__device__ __forceinline__ unsigned int pk2(float a, float b){
  return (unsigned int)f2bf(a) | ((unsigned int)f2bf(b) << 16);
}

// async global->LDS, 16B per lane; LDS dest = wave-uniform base + lane*16 (m97/m104)
__device__ __forceinline__ void gload_lds16(const void* g, void* l){
  __builtin_amdgcn_global_load_lds(
      (const __attribute__((address_space(1))) void*)g,
      (__attribute__((address_space(3))) void*)l, 16, 0, 0);
}

// ---------------- mask format sniffing ----------------
__device__ __forceinline__ bool mask_at(const void* mp, int flag, int idx){
  return flag ? (((const unsigned char*)mp)[idx] != 0)
              : (((const unsigned int*)mp)[idx] != 0u);
}

__global__ __launch_bounds__(256) void sniff_mask_kernel(const unsigned int* __restrict__ m,
                                                         int* __restrict__ flag){
  __shared__ unsigned int red[256];
  unsigned int acc = 0u;
  for (int i = threadIdx.x; i < 8192; i += 256) acc |= m[i];
  red[threadIdx.x] = acc;
  __syncthreads();
  for (int s = 128; s > 0; s >>= 1){
    if ((int)threadIdx.x < s) red[threadIdx.x] |= red[threadIdx.x + s];
    __syncthreads();
  }
  if (threadIdx.x == 0){
    unsigned int o = red[0];
    *flag = (o > 1u && (o & 0xFEFEFEFEu) == 0u) ? 1 : 0;
  }
}

// ---------------- hidden f32 -> bf16 ----------------
__global__ __launch_bounds__(256) void cvt_hidden_kernel(const float* __restrict__ src,
                                                         u16* __restrict__ dst){
  int idx = blockIdx.x * 256 + threadIdx.x;
  for (int base = idx * 8; base < 25165824; base += 2048 * 256 * 8){
    float4 a = *(const float4*)&src[base];
    float4 b = *(const float4*)&src[base + 4];
    uint4 o;
    o.x = pk2(a.x, a.y); o.y = pk2(a.z, a.w);
    o.z = pk2(b.x, b.y); o.w = pk2(b.z, b.w);
    *(uint4*)&dst[base] = o;
  }
}

// ---------------- W (k-major 768x768 f32) -> WT (n-major bf16), 3 mats ----------------
__global__ __launch_bounds__(256) void cvt_wT_kernel(const float* __restrict__ W0,
    const float* __restrict__ W1, const float* __restrict__ W2, u16* __restrict__ wT){
  __shared__ float tile[64][65];
  const float* Wsel = blockIdx.z == 0 ? W0 : (blockIdx.z == 1 ? W1 : W2);
  const int t = threadIdx.x;
  const int kt0 = blockIdx.x * 64, nt0 = blockIdx.y * 64;
  { const int row = t >> 2, c16 = (t & 3) * 16;
#pragma unroll
    for (int j = 0; j < 4; ++j){
      float4 v = *(const float4*)&Wsel[(size_t)(kt0 + row) * 768 + nt0 + c16 + j * 4];
      tile[row][c16 + j*4 + 0] = v.x; tile[row][c16 + j*4 + 1] = v.y;
      tile[row][c16 + j*4 + 2] = v.z; tile[row][c16 + j*4 + 3] = v.w;
    } }
  __syncthreads();
  { const int nl = t >> 2, k16 = (t & 3) * 16;
    unsigned int o[8];
#pragma unroll
    for (int j = 0; j < 8; ++j)
      o[j] = pk2(tile[k16 + 2*j][nl], tile[k16 + 2*j + 1][nl]);
    u16* dst = wT + (size_t)blockIdx.z * 589824 + (size_t)(nt0 + nl) * 768 + kt0 + k16;
    *(uint4*)dst       = make_uint4(o[0], o[1], o[2], o[3]);
    *(uint4*)(dst + 8) = make_uint4(o[4], o[5], o[6], o[7]); }
}

// ---------------- fused 3-projection MFMA GEMM (global_load_lds + XOR swizzle) ----------
// 1D grid 4608 = 8 XCD chunks x 576 (bijective T1 swizzle). swz x-major: 256 M-tiles,
// 18 N-tiles (3 proj x 6). LDS tiles UNPADDED [128][64] bf16 (rows 128B), staged via
// global_load_lds with source-side XOR swizzle slot^=(row&7); reads apply same XOR
// (T21 both-sides). Frag read audited: 2 lanes/bank (free, m136).
__global__ __launch_bounds__(256) void proj_mfma_kernel(
    const u16* __restrict__ hb, const u16* __restrict__ wT,
    const float* __restrict__ bq, const float* __restrict__ bk, const float* __restrict__ bv,
    u16* __restrict__ qb, u16* __restrict__ kb, u16* __restrict__ vb){
  __shared__ u16 As[128 * 64];
  __shared__ u16 Bs[128 * 64];
  const int t = threadIdx.x;
  const int id = blockIdx.x;
  const int swz = (id & 7) * 576 + (id >> 3);
  const int mt = swz & 255, nt = swz >> 8;
  const int p  = nt / 6;
  const int c0 = (nt % 6) * 128;
  const int r0 = mt * 128;
  const float* bias = p == 0 ? bq : (p == 1 ? bk : bv);
  u16* dst = p == 0 ? qb : (p == 1 ? kb : vb);
  const u16* wTp = wT + (size_t)p * 589824;

  const int lane = t & 63, w = t >> 6;
  const int l15 = lane & 15, lg = lane >> 4;
  const int wr = w >> 1, wc = w & 1;
  const int lrc = lane >> 3, slot = lane & 7;   // staging row-in-chunk / 16B slot

  f32x4 acc[4][4] = {};

  for (int k0 = 0; k0 < 768; k0 += 64){
#pragma unroll
    for (int c = 0; c < 4; ++c){
      int chunk = w * 4 + c;                    // 16 chunks of 8 rows each
      int ldsrow = chunk * 8 + lrc;             // 0..127
      int slotg = slot ^ (ldsrow & 7);
      gload_lds16(&hb [(size_t)(r0 + ldsrow) * 768 + k0 + slotg * 8], &As[chunk * 512]);
      gload_lds16(&wTp[(size_t)(c0 + ldsrow) * 768 + k0 + slotg * 8], &Bs[chunk * 512]);
    }
    __syncthreads();
    bf16x8 af[4][2], bf[4][2];
#pragma unroll
    for (int mf = 0; mf < 4; ++mf)
#pragma unroll
      for (int ks = 0; ks < 2; ++ks)
        af[mf][ks] = *(const bf16x8*)&As[(wr*64 + mf*16 + l15) * 64 + (((ks*4 + lg) ^ (l15 & 7)) * 8)];
#pragma unroll
    for (int nf = 0; nf < 4; ++nf)
#pragma unroll
      for (int ks = 0; ks < 2; ++ks)
        bf[nf][ks] = *(const bf16x8*)&Bs[(wc*64 + nf*16 + l15) * 64 + (((ks*4 + lg) ^ (l15 & 7)) * 8)];
#pragma unroll
    for (int ks = 0; ks < 2; ++ks)
#pragma unroll
      for (int mf = 0; mf < 4; ++mf)
#pragma unroll
        for (int nf = 0; nf < 4; ++nf)
          acc[mf][nf] = MFMA16(af[mf][ks], bf[nf][ks], acc[mf][nf]);
    __syncthreads();
  }
#pragma unroll
  for (int nf = 0; nf < 4; ++nf){
    int c = c0 + wc*64 + nf*16 + l15;
    float bsv = bias[c];
    int hh = c >> 6, dd = c & 63;
#pragma unroll
    for (int mf = 0; mf < 4; ++mf){
      int rbase = r0 + wr*64 + mf*16 + lg*4;
#pragma unroll
      for (int r = 0; r < 4; ++r){
        int row = rbase + r;
        int s = row >> 3, b = row & 7;          // row = s*B + b
        dst[((size_t)(b * 12 + hh) * 4096 + s) * 64 + dd] = f2bf(acc[mf][nf][r] + bsv);
      }
    }
  }
}

// ---------------- v [bh][s][64] -> vt [bh][d][4096] (bf16 bit-copy transpose) ----------------
__global__ __launch_bounds__(256) void vt_kernel(const u16* __restrict__ vb, u16* __restrict__ vtb){
  __shared__ u16 tile[64][72];
  const int t = threadIdx.x;
  const int stile = blockIdx.x, bh = blockIdx.y;
  { const int sl = t >> 2, q = (t & 3) * 16;
    const u16* src = &vb[((size_t)bh * 4096 + stile * 64 + sl) * 64 + q];
    *(uint4*)&tile[sl][q]     = *(const uint4*)src;
    *(uint4*)&tile[sl][q + 8] = *(const uint4*)(src + 8); }
  __syncthreads();
  { const int d = t >> 2, sq = (t & 3) * 16;
    unsigned int o[8];
#pragma unroll
    for (int j = 0; j < 8; ++j){
      unsigned int lo = tile[sq + 2*j][d], hi = tile[sq + 2*j + 1][d];
      o[j] = lo | (hi << 16);
    }
    u16* dst = vtb + ((size_t)bh * 64 + d) * 4096 + stile * 64 + sq;
    *(uint4*)dst       = make_uint4(o[0], o[1], o[2], o[3]);
    *(uint4*)(dst + 8) = make_uint4(o[4], o[5], o[6], o[7]); }
}

// ---------------- local windowed attention, MFMA flash-style ----------------
// 1D grid 3072 = 8 XCD chunks x 384 (12 bh-groups of 32 windows each -> K/V L2 reuse).
// K/V tiles unpadded [64][64] staged via global_load_lds + XOR swizzle (as proj).
// T5 setprio around MFMA clusters.
__global__ __launch_bounds__(256) void local_mfma_kernel(
    const u16* __restrict__ qb, const u16* __restrict__ kb, const u16* __restrict__ vtb,
    const void* __restrict__ maskp, const int* __restrict__ flagp,
    float* __restrict__ out){
  __shared__ u16 Ks[64 * 64];
  __shared__ u16 Vs[64 * 64];
  __shared__ u16 Ps[4][32][72];
  __shared__ float kpen[384];
  __shared__ float qpen_s[128];
  const int t = threadIdx.x;
  const int id = blockIdx.x;
  const int swz = (id & 7) * 384 + (id >> 3);
  const int n_i = swz & 31, bh = swz >> 5;
  const int b_i = bh / 12, h = bh % 12;
  const int flag = *flagp;
  const int w = t >> 6, lane = t & 63, l15 = lane & 15, lg = lane >> 4;
  const int lrc = lane >> 3, slot = lane & 7;
  const int jbase0 = n_i * 128 - 128;

  if (t < 128) qpen_s[t] = mask_at(maskp, flag, b_i * 4096 + n_i * 128 + t) ? 1.f : 0.f;
  for (int j = t; j < 384; j += 256){
    int jp = jbase0 + j;
    kpen[j] = (jp < 0 || jp >= 4096 || mask_at(maskp, flag, b_i * 4096 + jp)) ? 1.f : 0.f;
  }
  __syncthreads();

  bf16x8 aq[2][2];
#pragma unroll
  for (int mf = 0; mf < 2; ++mf)
#pragma unroll
    for (int ks = 0; ks < 2; ++ks)
      aq[mf][ks] = *(const bf16x8*)&qb[((size_t)bh * 4096 + n_i*128 + w*32 + mf*16 + l15) * 64 + ks*32 + lg*8];

  float qp[2][4];
#pragma unroll
  for (int mf = 0; mf < 2; ++mf)
#pragma unroll
    for (int r = 0; r < 4; ++r)
      qp[mf][r] = qpen_s[w*32 + mf*16 + lg*4 + r];

  f32x4 O[2][4] = {};
  float mrow[2][4], lrow[2][4];
#pragma unroll
  for (int mf = 0; mf < 2; ++mf)
#pragma unroll
    for (int r = 0; r < 4; ++r){ mrow[mf][r] = -FLT_MAX; lrow[mf][r] = 0.f; }

  for (int jt = 0; jt < 6; ++jt){
    const int jb = jbase0 + jt * 64;
    if (jb < 0 || jb >= 4096) continue;      // block-uniform: barriers balanced
#pragma unroll
    for (int c = 0; c < 2; ++c){
      int chunk = w * 2 + c;                 // 8 chunks of 8 rows
      int ldsrow = chunk * 8 + lrc;          // 0..63
      int slotg = slot ^ (ldsrow & 7);
      gload_lds16(&kb [((size_t)bh * 4096 + jb + ldsrow) * 64 + slotg * 8], &Ks[chunk * 512]);
      gload_lds16(&vtb[((size_t)bh * 64 + ldsrow) * 4096 + jb + slotg * 8], &Vs[chunk * 512]);
    }
    __syncthreads();

    f32x4 dt[2][4] = {};
    __builtin_amdgcn_s_setprio(1);
#pragma unroll
    for (int ks = 0; ks < 2; ++ks)
#pragma unroll
      for (int nf = 0; nf < 4; ++nf){
        bf16x8 bk_ = *(const bf16x8*)&Ks[(nf*16 + l15) * 64 + (((ks*4 + lg) ^ (l15 & 7)) * 8)];
        dt[0][nf] = MFMA16(aq[0][ks], bk_, dt[0][nf]);
        dt[1][nf] = MFMA16(aq[1][ks], bk_, dt[1][nf]);
      }
    __builtin_amdgcn_s_setprio(0);
#pragma unroll
    for (int nf = 0; nf < 4; ++nf){
      float kp = kpen[jt*64 + nf*16 + l15];
#pragma unroll
      for (int mf = 0; mf < 2; ++mf)
#pragma unroll
        for (int r = 0; r < 4; ++r){
          float vv = dt[mf][nf][r] * 0.125f;
          dt[mf][nf][r] = (qp[mf][r] + kp == 0.f) ? vv : -FLT_MAX;
        }
    }
#pragma unroll
    for (int mf = 0; mf < 2; ++mf)
#pragma unroll
      for (int r = 0; r < 4; ++r){
        float tm = fmaxf(fmaxf(dt[mf][0][r], dt[mf][1][r]), fmaxf(dt[mf][2][r], dt[mf][3][r]));
        tm = fmaxf(tm, __shfl_xor(tm, 1));
        tm = fmaxf(tm, __shfl_xor(tm, 2));
        tm = fmaxf(tm, __shfl_xor(tm, 4));
        tm = fmaxf(tm, __shfl_xor(tm, 8));
        float mold = mrow[mf][r];
        float mnew = fmaxf(mold, tm);
        float scl = __expf(mold - mnew);     // exp(0)=1 when both -FLT_MAX
        mrow[mf][r] = mnew;
        float ps = 0.f;
#pragma unroll
        for (int nf = 0; nf < 4; ++nf){
          float pv = __expf(dt[mf][nf][r] - mnew);
          ps += pv;
          Ps[w][mf*16 + lg*4 + r][nf*16 + l15] = f2bf(pv);
          O[mf][nf][r] *= scl;
        }
        ps += __shfl_xor(ps, 1);
        ps += __shfl_xor(ps, 2);
        ps += __shfl_xor(ps, 4);
        ps += __shfl_xor(ps, 8);
        lrow[mf][r] = lrow[mf][r] * scl + ps;
      }
    __builtin_amdgcn_s_setprio(1);
#pragma unroll
    for (int ks = 0; ks < 2; ++ks){
      bf16x8 ap0 = *(const bf16x8*)&Ps[w][l15]     [ks*32 + lg*8];
      bf16x8 ap1 = *(const bf16x8*)&Ps[w][16 + l15][ks*32 + lg*8];
#pragma unroll
      for (int nf = 0; nf < 4; ++nf){
        bf16x8 bv_ = *(const bf16x8*)&Vs[(nf*16 + l15) * 64 + (((ks*4 + lg) ^ (l15 & 7)) * 8)];
        O[0][nf] = MFMA16(ap0, bv_, O[0][nf]);
        O[1][nf] = MFMA16(ap1, bv_, O[1][nf]);
      }
    }
    __builtin_amdgcn_s_setprio(0);
    __syncthreads();
  }

  const float noor = (n_i == 0 || n_i == 31) ? 128.f : 0.f;
#pragma unroll
  for (int mf = 0; mf < 2; ++mf)
#pragma unroll
    for (int r = 0; r < 4; ++r){
      float lf = lrow[mf][r] + ((mrow[mf][r] <= -FLT_MAX) ? noor : 0.f);
      float inv = 1.f / lf;
      int srow = n_i*128 + w*32 + mf*16 + lg*4 + r;
      float* op = &out[(size_t)srow * (8 * 768) + b_i * 768 + h * 64];
#pragma unroll
      for (int nf = 0; nf < 4; ++nf)
        op[nf*16 + l15] = O[mf][nf][r] * inv;
    }
}

// ---------------- global token-0 attention: gq, split-S partials, combine ----------------
__global__ __launch_bounds__(256) void gq_kernel(const float* __restrict__ hid,
    const float* __restrict__ Wgq, const float* __restrict__ bgq, float* __restrict__ gq){
  __shared__ float hs[768];
  __shared__ float red[256];
  const int t = threadIdx.x, bh = blockIdx.x, b_i = bh / 12, h = bh % 12;
  for (int c = t; c < 768; c += 256) hs[c] = hid[(size_t)b_i * 768 + c];
  __syncthreads();
  const int dd = t & 63, part = t >> 6;
  float acc = 0.f;
  for (int c = part * 192; c < part * 192 + 192; ++c)
    acc += hs[c] * Wgq[(size_t)c * 768 + h * 64 + dd];
  red[t] = acc;
  __syncthreads();
  if (t < 64)
    gq[bh * 64 + t] = (red[t] + red[t+64] + red[t+128] + red[t+192] + bgq[h*64 + t]) * 0.125f;
}

__global__ __launch_bounds__(256) void gpart_kernel(const float* __restrict__ gq,
    const u16* __restrict__ kb, const u16* __restrict__ vb,
    const void* __restrict__ maskp, const int* __restrict__ flagp,
    float* __restrict__ gp_out){
  __shared__ float gqs[64];
  __shared__ float sc[512];
  __shared__ float red[256];
  const int t = threadIdx.x, bh = blockIdx.x, chunk = blockIdx.y;
  const int b_i = bh / 12;
  const int flag = *flagp;
  if (t < 64) gqs[t] = gq[bh * 64 + t];
  __syncthreads();
#pragma unroll
  for (int i = 0; i < 2; ++i){
    int sl = i * 256 + t;
    int s = chunk * 512 + sl;
    const uint4* kr = (const uint4*)&kb[((size_t)bh * 4096 + s) * 64];
    float dot = 0.f;
#pragma unroll
    for (int u = 0; u < 8; ++u){
      uint4 x = kr[u];
      dot += gqs[u*8+0]*bflo(x.x) + gqs[u*8+1]*bfhi(x.x);
      dot += gqs[u*8+2]*bflo(x.y) + gqs[u*8+3]*bfhi(x.y);
      dot += gqs[u*8+4]*bflo(x.z) + gqs[u*8+5]*bfhi(x.z);
      dot += gqs[u*8+6]*bflo(x.w) + gqs[u*8+7]*bfhi(x.w);
    }
    sc[sl] = mask_at(maskp, flag, b_i * 4096 + s) ? -FLT_MAX : dot;
  }
  __syncthreads();
  float m = fmaxf(sc[t], sc[t + 256]);
  red[t] = m; __syncthreads();
  for (int st = 128; st > 0; st >>= 1){ if (t < st) red[t] = fmaxf(red[t], red[t + st]); __syncthreads(); }
  const float mc = red[0];
  __syncthreads();
  float ls = 0.f;
#pragma unroll
  for (int i = 0; i < 2; ++i){
    int sl = i * 256 + t;
    float p = __expf(sc[sl] - mc);
    sc[sl] = p; ls += p;
  }
  red[t] = ls; __syncthreads();
  for (int st = 128; st > 0; st >>= 1){ if (t < st) red[t] += red[t + st]; __syncthreads(); }
  const float lc = red[0];
  __syncthreads();
  const int dd = t & 63, part = t >> 6;
  float o = 0.f;
  for (int i2 = 0; i2 < 128; ++i2){
    int sl = part * 128 + i2;
    o += sc[sl] * bf2f(vb[((size_t)bh * 4096 + chunk * 512 + sl) * 64 + dd]);
  }
  red[t] = o; __syncthreads();
  float* gp = gp_out + ((size_t)bh * 8 + chunk) * 66;
  if (t == 0){ gp[0] = mc; gp[1] = lc; }
  if (t < 64) gp[2 + t] = red[t] + red[t+64] + red[t+128] + red[t+192];
}

__global__ __launch_bounds__(64) void greduce_kernel(const float* __restrict__ gp_in,
                                                     float* __restrict__ out){
  const int t = threadIdx.x, bh = blockIdx.x, b_i = bh / 12, h = bh % 12;
  const float* gp = gp_in + (size_t)bh * 8 * 66;
  float mg = -FLT_MAX;
#pragma unroll
  for (int c = 0; c < 8; ++c) mg = fmaxf(mg, gp[c * 66]);
  float lg = 0.f, o = 0.f;
#pragma unroll
  for (int c = 0; c < 8; ++c){
    float wv = __expf(gp[c * 66] - mg);
    lg += gp[c * 66 + 1] * wv;
    o  += gp[c * 66 + 2 + t] * wv;
  }
  out[(size_t)b_i * 768 + h * 64 + t] = o / lg;
}

// ---------------- launch ----------------
extern "C" void kernel_launch(void* const* d_in, const int* in_sizes, int n_in,
                              void* d_out, int out_size, void* d_ws, size_t ws_size,
                              hipStream_t stream) {
  const float* hid   = (const float*)d_in[0];
  const void*  maskp = d_in[1];
  const float* Wq  = (const float*)d_in[2];
  const float* Wk  = (const float*)d_in[3];
  const float* Wv  = (const float*)d_in[4];
  const float* Wgq = (const float*)d_in[5];
  const float* bq  = (const float*)d_in[6];
  const float* bk  = (const float*)d_in[7];
  const float* bv  = (const float*)d_in[8];
  const float* bgq = (const float*)d_in[9];
  float* out = (float*)d_out;

  char* wsb = (char*)d_ws;
  int* flag   = (int*)wsb;                       // 256 B
  u16* hb     = (u16*)(wsb + 256);               // 50331648 B
  u16* wT     = (u16*)(wsb + 50331904);          // 3538944 B
  u16* qb     = (u16*)(wsb + 53870848);          // 50331648 B
  u16* kb     = (u16*)(wsb + 104202496);         // 50331648 B
  u16* vb     = (u16*)(wsb + 154534144);         // 50331648 B
  u16* vtb    = (u16*)(wsb + 204865792);         // 50331648 B
  float* gq   = (float*)(wsb + 255197440);       // 24576 B
  float* gpart = (float*)(wsb + 255222016);      // 202752 B  (end ~255.4 MB)

  sniff_mask_kernel<<<1, 256, 0, stream>>>((const unsigned int*)maskp, flag);
  cvt_hidden_kernel<<<2048, 256, 0, stream>>>(hid, hb);
  cvt_wT_kernel<<<dim3(12, 12, 3), 256, 0, stream>>>(Wq, Wk, Wv, wT);
  proj_mfma_kernel<<<4608, 256, 0, stream>>>(hb, wT, bq, bk, bv, qb, kb, vb);
  vt_kernel<<<dim3(64, 96), 256, 0, stream>>>(vb, vtb);
  gq_kernel<<<96, 256, 0, stream>>>(hid, Wgq, bgq, gq);
  local_mfma_kernel<<<3072, 256, 0, stream>>>(qb, kb, vtb, maskp, flag, out);
  gpart_kernel<<<dim3(96, 8), 256, 0, stream>>>(gq, kb, vb, maskp, flag, gpart);
  greduce_kernel<<<96, 64, 0, stream>>>(gpart, out);
}